// Round 2
// baseline (525.319 us; speedup 1.0000x reference)
//
#include <hip/hip_runtime.h>

// Lattice: 32^4 sites, F=8 channels, complex 3-vectors, 4 link directions.
// x:  (8, 32,32,32,32, 3)  complex (split re/im arrays)
// U:  (4, 32,32,32,32, 3,3) complex (split re/im arrays)
// out: (2, 8, 32,32,32,32, 3) float32  [re block then im block]
//
// Round 2: MLP restructure. Round-1 used one shared U temp -> VGPR=40,
// serialized load->use round trips, 3.15 TB/s (latency-bound). Here every
// load gets a distinct register destination so ~75 vmem ops are in flight
// per wave; __launch_bounds__(256,2) caps at 256 VGPR (2 waves/SIMD).
// Output is write-once -> non-temporal stores to keep U/x resident in L2/L3.

#define L 32
#define V (32*32*32*32)          // 1,048,576 sites
#define V3 (V*3)
#define SX (32*32*32)            // +1 in x  -> +32768 sites
#define SY (32*32)               // +1 in y  -> +1024
#define SZ 32                    // +1 in z  -> +32
// t stride = 1

__device__ __forceinline__ void load_vec(const float* __restrict__ xr,
                                         const float* __restrict__ xi,
                                         int f, int s, float vr[3], float vi[3]) {
    long b = (long)f * V3 + (long)s * 3;
#pragma unroll
    for (int k = 0; k < 3; ++k) { vr[k] = xr[b+k]; vi[k] = xi[b+k]; }
}

__device__ __forceinline__ void load_U(const float* __restrict__ Ur_g,
                                       const float* __restrict__ Ui_g,
                                       int mu, int s, float Ur[9], float Ui[9]) {
    long b = (long)mu * (long)V * 9 + (long)s * 9;
#pragma unroll
    for (int k = 0; k < 9; ++k) { Ur[k] = Ur_g[b+k]; Ui[k] = Ui_g[b+k]; }
}

// y = U v   (complex 3x3 times complex 3-vector)
__device__ __forceinline__ void matvec(const float Ur[9], const float Ui[9],
                                       const float vr[3], const float vi[3],
                                       float yr[3], float yi[3]) {
#pragma unroll
    for (int a = 0; a < 3; ++a) {
        float ar = 0.f, ai = 0.f;
#pragma unroll
        for (int b = 0; b < 3; ++b) {
            float ur = Ur[a*3+b], ui = Ui[a*3+b];
            ar += ur * vr[b] - ui * vi[b];
            ai += ur * vi[b] + ui * vr[b];
        }
        yr[a] = ar; yi[a] = ai;
    }
}

// y = U^dag v  (conjugate transpose)
__device__ __forceinline__ void matvec_dag(const float Ur[9], const float Ui[9],
                                           const float vr[3], const float vi[3],
                                           float yr[3], float yi[3]) {
#pragma unroll
    for (int a = 0; a < 3; ++a) {
        float ar = 0.f, ai = 0.f;
#pragma unroll
        for (int b = 0; b < 3; ++b) {
            float ur = Ur[b*3+a], ui = Ui[b*3+a];   // transpose
            ar += ur * vr[b] + ui * vi[b];          // conj
            ai += ur * vi[b] - ui * vr[b];
        }
        yr[a] = ar; yi[a] = ai;
    }
}

__device__ __forceinline__ void store_out(float* __restrict__ outr,
                                          float* __restrict__ outi,
                                          int f, int s, float sc,
                                          const float yr[3], const float yi[3]) {
    long b = (long)f * V3 + (long)s * 3;
#pragma unroll
    for (int k = 0; k < 3; ++k) {
        __builtin_nontemporal_store(sc * yr[k], &outr[b+k]);
        __builtin_nontemporal_store(sc * yi[k], &outi[b+k]);
    }
}

__global__ __launch_bounds__(256, 2)
void transport_kernel(const float* __restrict__ xr,
                      const float* __restrict__ xi,
                      const float* __restrict__ Urg,
                      const float* __restrict__ Uig,
                      float* __restrict__ outr,
                      float* __restrict__ outi) {
    int s = blockIdx.x * blockDim.x + threadIdx.x;

    int t = s & 31;
    int z = (s >> 5) & 31;
    int y = (s >> 10) & 31;
    int x = (s >> 15) & 31;

    int s_xp = s + ((x == 31) ? -(31*SX) : SX);
    int s_xm = s + ((x == 0)  ?  (31*SX) : -SX);
    int s_yp = s + ((y == 31) ? -(31*SY) : SY);
    int s_ym = s + ((y == 0)  ?  (31*SY) : -SY);
    int s_zp = s + ((z == 31) ? -(31*SZ) : SZ);
    int s_tp = s + ((t == 31) ? -31 : 1);
    int s_xpyp = s_yp + ((x == 31) ? -(31*SX) : SX);

    float eta1 = (x & 1) ? -1.f : 1.f;            // (-1)^x0
    float eta2 = ((x + y) & 1) ? -1.f : 1.f;      // (-1)^(x0+x1)
    float eta3 = ((x + y + z) & 1) ? -1.f : 1.f;  // (-1)^(x0+x1+x2)

    // ---------------- load phase: all independent, distinct registers ----------------
    float U0r[9], U0i[9];   load_U(Urg, Uig, 0, s,    U0r, U0i);   // ch1, ch7(outer)
    float U1r[9], U1i[9];   load_U(Urg, Uig, 1, s,    U1r, U1i);   // ch2, ch7(outer)
    float Uyr[9], Uyi[9];   load_U(Urg, Uig, 0, s_yp, Uyr, Uyi);   // ch7(inner)
    float U2r[9], U2i[9];   load_U(Urg, Uig, 2, s,    U2r, U2i);   // ch3
    float U3r[9], U3i[9];   load_U(Urg, Uig, 3, s,    U3r, U3i);   // ch4
    float Uxr[9], Uxi[9];   load_U(Urg, Uig, 0, s_xm, Uxr, Uxi);   // ch5
    float Umr[9], Umi[9];   load_U(Urg, Uig, 1, s_ym, Umr, Umi);   // ch6

    float x0r[3], x0i[3];   load_vec(xr, xi, 0, s,      x0r, x0i);
    float x1r[3], x1i[3];   load_vec(xr, xi, 1, s_xp,   x1r, x1i);
    float x2r[3], x2i[3];   load_vec(xr, xi, 2, s_yp,   x2r, x2i);
    float x3r[3], x3i[3];   load_vec(xr, xi, 3, s_zp,   x3r, x3i);
    float x4r[3], x4i[3];   load_vec(xr, xi, 4, s_tp,   x4r, x4i);
    float x5r[3], x5i[3];   load_vec(xr, xi, 5, s_xm,   x5r, x5i);
    float x6r[3], x6i[3];   load_vec(xr, xi, 6, s_ym,   x6r, x6i);
    float x7r[3], x7i[3];   load_vec(xr, xi, 7, s_xpyp, x7r, x7i);

    // ---------------- compute + store per channel ----------------
    float yr[3], yi[3];

    // ch0: identity
    store_out(outr, outi, 0, s, 1.f, x0r, x0i);

    // ch1: U0(x) x1(x+xhat), eta0 = 1
    matvec(U0r, U0i, x1r, x1i, yr, yi);
    store_out(outr, outi, 1, s, 1.f, yr, yi);

    // ch2: eta1(x) U1(x) x2(x+yhat)
    matvec(U1r, U1i, x2r, x2i, yr, yi);
    store_out(outr, outi, 2, s, eta1, yr, yi);

    // ch7: eta1(x) * U1(x) @ U0(x+yhat) @ x7(x+xhat+yhat)
    {
        float gr[3], gi[3];
        matvec(Uyr, Uyi, x7r, x7i, gr, gi);       // g = U0(x+yhat) x7
        matvec(U1r, U1i, gr, gi, yr, yi);         // y = U1(x) g
        store_out(outr, outi, 7, s, eta1, yr, yi);
    }

    // ch3: eta2(x) U2(x) x3(x+zhat)
    matvec(U2r, U2i, x3r, x3i, yr, yi);
    store_out(outr, outi, 3, s, eta2, yr, yi);

    // ch4: eta3(x) U3(x) x4(x+that)
    matvec(U3r, U3i, x4r, x4i, yr, yi);
    store_out(outr, outi, 4, s, eta3, yr, yi);

    // ch5: U0^dag(x-xhat) x5(x-xhat), eta0 = 1
    matvec_dag(Uxr, Uxi, x5r, x5i, yr, yi);
    store_out(outr, outi, 5, s, 1.f, yr, yi);

    // ch6: eta1(x-yhat) = eta1(x); U1^dag(x-yhat) x6(x-yhat)
    matvec_dag(Umr, Umi, x6r, x6i, yr, yi);
    store_out(outr, outi, 6, s, eta1, yr, yi);
}

extern "C" void kernel_launch(void* const* d_in, const int* in_sizes, int n_in,
                              void* d_out, int out_size, void* d_ws, size_t ws_size,
                              hipStream_t stream) {
    const float* xr  = (const float*)d_in[0];
    const float* xi  = (const float*)d_in[1];
    const float* Urg = (const float*)d_in[2];
    const float* Uig = (const float*)d_in[3];
    float* outr = (float*)d_out;
    float* outi = (float*)d_out + (long)8 * V3;   // imag block after real block

    const int block = 256;
    const int grid = V / block;                   // 4096 blocks
    transport_kernel<<<grid, block, 0, stream>>>(xr, xi, Urg, Uig, outr, outi);
}